// Round 1
// baseline (513.890 us; speedup 1.0000x reference)
//
#include <hip/hip_runtime.h>
#include <math.h>

typedef short bf16x8 __attribute__((ext_vector_type(8)));
typedef float f32x4 __attribute__((ext_vector_type(4)));

// ---------- helpers ----------
__device__ __forceinline__ unsigned short f2bf(float f) {
    union { float f; unsigned u; } v; v.f = f;
    unsigned r = v.u + 0x7fffu + ((v.u >> 16) & 1u);   // RNE
    return (unsigned short)(r >> 16);
}

// ---------- fp32 -> bf16 convert (vectorized x4) ----------
__global__ void cvt_f32_bf16(const float* __restrict__ src, unsigned short* __restrict__ dst, int n) {
    int i = (blockIdx.x * blockDim.x + threadIdx.x) * 4;
    if (i < n) {
        float4 f = *(const float4*)(src + i);
        ushort4 o;
        o.x = f2bf(f.x); o.y = f2bf(f.y); o.z = f2bf(f.z); o.w = f2bf(f.w);
        *(ushort4*)(dst + i) = o;
    }
}

// ---------- GEMM: C[M,N] = A[M,K] @ W[N,K]^T + bias, bf16 inputs ----------
// 128x128 block tile, 4 waves of 64x64, BK=32, 16x16x32 bf16 MFMA.
// LDS rows padded to 40 elems (80B = 20 dwords) -> b128 reads ~2-way (free).
__global__ __launch_bounds__(256) void gemm_bt(
        const unsigned short* __restrict__ A, const unsigned short* __restrict__ W,
        const float* __restrict__ bias, float* __restrict__ outF,
        unsigned short* __restrict__ outB, int M, int N, int K) {
    __shared__ unsigned short As[128][40];
    __shared__ unsigned short Ws[128][40];
    const int m0 = blockIdx.y * 128, n0 = blockIdx.x * 128;
    const int tid = threadIdx.x, lane = tid & 63, w = tid >> 6;
    const int quad = lane >> 4, lc = lane & 15;
    const int wr = (w >> 1) * 64, wc = (w & 1) * 64;

    f32x4 acc[4][4] = {};

    for (int k0 = 0; k0 < K; k0 += 32) {
        __syncthreads();
        #pragma unroll
        for (int i = 0; i < 2; ++i) {
            int c = tid + 256 * i;            // 0..511
            int row = c >> 2, col8 = (c & 3) * 8;
            *(bf16x8*)&As[row][col8] = *(const bf16x8*)(A + (size_t)(m0 + row) * K + k0 + col8);
            *(bf16x8*)&Ws[row][col8] = *(const bf16x8*)(W + (size_t)(n0 + row) * K + k0 + col8);
        }
        __syncthreads();
        bf16x8 af[4], bw[4];
        #pragma unroll
        for (int i = 0; i < 4; ++i) af[i] = *(const bf16x8*)&As[wr + i * 16 + lc][quad * 8];
        #pragma unroll
        for (int j = 0; j < 4; ++j) bw[j] = *(const bf16x8*)&Ws[wc + j * 16 + lc][quad * 8];
        #pragma unroll
        for (int i = 0; i < 4; ++i)
            #pragma unroll
            for (int j = 0; j < 4; ++j)
                acc[i][j] = __builtin_amdgcn_mfma_f32_16x16x32_bf16(af[i], bw[j], acc[i][j], 0, 0, 0);
    }

    #pragma unroll
    for (int j = 0; j < 4; ++j) {
        int col = n0 + wc + j * 16 + lc;
        float bj = bias[col];
        #pragma unroll
        for (int i = 0; i < 4; ++i) {
            int rowb = m0 + wr + i * 16 + quad * 4;
            #pragma unroll
            for (int r = 0; r < 4; ++r) {
                float v = acc[i][j][r] + bj;
                size_t idx = (size_t)(rowb + r) * N + col;
                if (outB) outB[idx] = f2bf(v);
                else      outF[idx] = v;
            }
        }
    }
}

// ---------- flash attention ----------
// Q,K,V: (B*T, C) bf16 where head h occupies cols [h*64, h*64+64)
// grid: (T/64, B*NH); block: 256 (4 waves); wave w owns Q rows qt*64+w*16 .. +15
__global__ __launch_bounds__(256) void attn_kernel(
        const unsigned short* __restrict__ Q, const unsigned short* __restrict__ K,
        const unsigned short* __restrict__ V, const int* __restrict__ tmask,
        unsigned short* __restrict__ O) {
    const int T = 2048, C = 1024;
    __shared__ unsigned short Kl[64][72];   // [kv][d]
    __shared__ unsigned short VT[64][72];   // [d][kv]
    __shared__ unsigned short Pl[4][16][72];// per-wave P (16 q rows x 64 kv)
    __shared__ float maskf[64];

    const int qt = blockIdx.x;        // q tile (64 rows)
    const int bn = blockIdx.y;        // b*16 + head
    const int b = bn >> 4, h = bn & 15;
    const int tid = threadIdx.x, w = tid >> 6, lane = tid & 63;
    const int quad = lane >> 4, lc = lane & 15;
    const float NEG_INF = -__builtin_inff();

    // Q A-frags for this wave's 16 rows (d halves)
    size_t qrow = (size_t)(b * T + qt * 64 + w * 16 + lc) * C + h * 64;
    bf16x8 qa0 = *(const bf16x8*)(Q + qrow + quad * 8);
    bf16x8 qa1 = *(const bf16x8*)(Q + qrow + 32 + quad * 8);

    f32x4 oacc[4] = {};
    float m_r[4] = {NEG_INF, NEG_INF, NEG_INF, NEG_INF};
    float l_r[4] = {0.f, 0.f, 0.f, 0.f};

    for (int kt = 0; kt <= qt; ++kt) {
        __syncthreads();
        // stage K tile (row-major) and V tile (transposed)
        {
            int r = tid >> 2, c16 = (tid & 3) * 16;
            size_t g = (size_t)(b * T + kt * 64 + r) * C + h * 64 + c16;
            *(bf16x8*)&Kl[r][c16]     = *(const bf16x8*)(K + g);
            *(bf16x8*)&Kl[r][c16 + 8] = *(const bf16x8*)(K + g + 8);
            bf16x8 v0 = *(const bf16x8*)(V + g);
            bf16x8 v1 = *(const bf16x8*)(V + g + 8);
            #pragma unroll
            for (int i = 0; i < 8; ++i) VT[c16 + i][r] = (unsigned short)v0[i];
            #pragma unroll
            for (int i = 0; i < 8; ++i) VT[c16 + 8 + i][r] = (unsigned short)v1[i];
        }
        if (tid < 64)
            maskf[tid] = tmask[b * T + kt * 64 + tid] ? 0.0f : NEG_INF;
        __syncthreads();

        // S = Q K^T  (4 col tiles of 16)
        f32x4 sacc[4] = {};
        #pragma unroll
        for (int j = 0; j < 4; ++j) {
            bf16x8 b0 = *(const bf16x8*)&Kl[j * 16 + lc][quad * 8];
            bf16x8 b1 = *(const bf16x8*)&Kl[j * 16 + lc][32 + quad * 8];
            sacc[j] = __builtin_amdgcn_mfma_f32_16x16x32_bf16(qa0, b0, sacc[j], 0, 0, 0);
            sacc[j] = __builtin_amdgcn_mfma_f32_16x16x32_bf16(qa1, b1, sacc[j], 0, 0, 0);
        }

        // scale + masks
        float s[4][4];
        const int qg_base = qt * 64 + w * 16 + quad * 4;
        #pragma unroll
        for (int j = 0; j < 4; ++j) {
            int kg = kt * 64 + j * 16 + lc;
            float madd = maskf[j * 16 + lc];
            #pragma unroll
            for (int r = 0; r < 4; ++r) {
                float sv = sacc[j][r] * 0.125f + madd;   // 1/sqrt(64)
                if (kg > qg_base + r) sv = NEG_INF;
                s[j][r] = sv;
            }
        }

        // online softmax per row (rows live across 16 lanes of the quad)
        #pragma unroll
        for (int r = 0; r < 4; ++r) {
            float mx = fmaxf(fmaxf(s[0][r], s[1][r]), fmaxf(s[2][r], s[3][r]));
            #pragma unroll
            for (int off = 1; off < 16; off <<= 1)
                mx = fmaxf(mx, __shfl_xor(mx, off, 64));
            float mnew = fmaxf(m_r[r], mx);
            float alpha = __expf(m_r[r] - mnew);
            m_r[r] = mnew;
            float ps = 0.f;
            #pragma unroll
            for (int j = 0; j < 4; ++j) {
                float p = __expf(s[j][r] - mnew);
                s[j][r] = p;
                ps += p;
            }
            #pragma unroll
            for (int off = 1; off < 16; off <<= 1)
                ps += __shfl_xor(ps, off, 64);
            l_r[r] = l_r[r] * alpha + ps;
            #pragma unroll
            for (int j = 0; j < 4; ++j) oacc[j][r] *= alpha;
        }

        // P: C-layout regs -> LDS -> A-layout frags (per-wave buffer, no barrier)
        #pragma unroll
        for (int j = 0; j < 4; ++j)
            #pragma unroll
            for (int r = 0; r < 4; ++r)
                Pl[w][quad * 4 + r][j * 16 + lc] = f2bf(s[j][r]);

        bf16x8 pa0 = *(const bf16x8*)&Pl[w][lc][quad * 8];
        bf16x8 pa1 = *(const bf16x8*)&Pl[w][lc][32 + quad * 8];
        #pragma unroll
        for (int j = 0; j < 4; ++j) {
            bf16x8 b0 = *(const bf16x8*)&VT[j * 16 + lc][quad * 8];
            bf16x8 b1 = *(const bf16x8*)&VT[j * 16 + lc][32 + quad * 8];
            oacc[j] = __builtin_amdgcn_mfma_f32_16x16x32_bf16(pa0, b0, oacc[j], 0, 0, 0);
            oacc[j] = __builtin_amdgcn_mfma_f32_16x16x32_bf16(pa1, b1, oacc[j], 0, 0, 0);
        }
    }

    // epilogue: O /= l, store bf16
    #pragma unroll
    for (int r = 0; r < 4; ++r) {
        float inv = 1.0f / l_r[r];
        size_t orow = (size_t)(b * T + qt * 64 + w * 16 + quad * 4 + r) * C + h * 64;
        #pragma unroll
        for (int j = 0; j < 4; ++j)
            O[orow + j * 16 + lc] = f2bf(oacc[j][r] * inv);
    }
}

extern "C" void kernel_launch(void* const* d_in, const int* in_sizes, int n_in,
                              void* d_out, int out_size, void* d_ws, size_t ws_size,
                              hipStream_t stream) {
    const float* x  = (const float*)d_in[0];
    const int* tm   = (const int*)d_in[1];
    const float* wq = (const float*)d_in[2]; const float* bq = (const float*)d_in[3];
    const float* wk = (const float*)d_in[4]; const float* bk = (const float*)d_in[5];
    const float* wv = (const float*)d_in[6]; const float* bv = (const float*)d_in[7];
    const float* wp = (const float*)d_in[8]; const float* bp = (const float*)d_in[9];
    float* out = (float*)d_out;

    const int Bv = 4, Tv = 2048, Cv = 1024;
    const size_t MT = (size_t)Bv * Tv;           // 8192 rows
    const size_t XN = MT * Cv;                   // 8388608
    const size_t WN = (size_t)Cv * Cv;           // 1048576

    // workspace layout (bf16 elements): xb | wq | wk | wv | wp | Q | K | V ; attn aliases xb
    unsigned short* xb  = (unsigned short*)d_ws;
    unsigned short* wqb = xb  + XN;
    unsigned short* wkb = wqb + WN;
    unsigned short* wvb = wkb + WN;
    unsigned short* wpb = wvb + WN;
    unsigned short* Qb  = wpb + WN;
    unsigned short* Kb  = Qb + XN;
    unsigned short* Vb  = Kb + XN;
    unsigned short* Ab  = xb;                    // attn output reuses xb

    cvt_f32_bf16<<<XN / 1024, 256, 0, stream>>>(x,  xb,  (int)XN);
    cvt_f32_bf16<<<WN / 1024, 256, 0, stream>>>(wq, wqb, (int)WN);
    cvt_f32_bf16<<<WN / 1024, 256, 0, stream>>>(wk, wkb, (int)WN);
    cvt_f32_bf16<<<WN / 1024, 256, 0, stream>>>(wv, wvb, (int)WN);
    cvt_f32_bf16<<<WN / 1024, 256, 0, stream>>>(wp, wpb, (int)WN);

    dim3 gg(Cv / 128, MT / 128);                 // (8, 64)
    gemm_bt<<<gg, 256, 0, stream>>>(xb, wqb, bq, nullptr, Qb, (int)MT, Cv, Cv);
    gemm_bt<<<gg, 256, 0, stream>>>(xb, wkb, bk, nullptr, Kb, (int)MT, Cv, Cv);
    gemm_bt<<<gg, 256, 0, stream>>>(xb, wvb, bv, nullptr, Vb, (int)MT, Cv, Cv);

    attn_kernel<<<dim3(Tv / 64, Bv * 16), 256, 0, stream>>>(Qb, Kb, Vb, tm, Ab);

    gemm_bt<<<gg, 256, 0, stream>>>(Ab, wpb, bp, out, nullptr, (int)MT, Cv, Cv);
}

// Round 2
// 336.326 us; speedup vs baseline: 1.5280x; 1.5280x over previous
//
#include <hip/hip_runtime.h>
#include <math.h>

typedef short bf16x8 __attribute__((ext_vector_type(8)));
typedef float f32x4 __attribute__((ext_vector_type(4)));

__device__ __forceinline__ unsigned short f2bf(float f) {
    union { float f; unsigned u; } v; v.f = f;
    unsigned r = v.u + 0x7fffu + ((v.u >> 16) & 1u);   // RNE
    return (unsigned short)(r >> 16);
}

__device__ __forceinline__ void gld_lds16(const unsigned short* g, const unsigned short* l) {
    __builtin_amdgcn_global_load_lds(
        (const __attribute__((address_space(1))) void*)g,
        (__attribute__((address_space(3))) void*)l, 16, 0, 0);
}

// ---------- fp32 -> bf16 converts ----------
__global__ void cvt_f32_bf16(const float* __restrict__ src, unsigned short* __restrict__ dst, int n) {
    int i = (blockIdx.x * blockDim.x + threadIdx.x) * 4;
    if (i < n) {
        float4 f = *(const float4*)(src + i);
        ushort4 o;
        o.x = f2bf(f.x); o.y = f2bf(f.y); o.z = f2bf(f.z); o.w = f2bf(f.w);
        *(ushort4*)(dst + i) = o;
    }
}

__global__ void cvt4_f32_bf16(const float* s0, const float* s1, const float* s2, const float* s3,
                              unsigned short* d0, unsigned short* d1, unsigned short* d2,
                              unsigned short* d3, int n) {
    const float* s; unsigned short* d;
    switch (blockIdx.y) {
        case 0: s = s0; d = d0; break;
        case 1: s = s1; d = d1; break;
        case 2: s = s2; d = d2; break;
        default: s = s3; d = d3; break;
    }
    int i = (blockIdx.x * blockDim.x + threadIdx.x) * 4;
    if (i < n) {
        float4 f = *(const float4*)(s + i);
        ushort4 o;
        o.x = f2bf(f.x); o.y = f2bf(f.y); o.z = f2bf(f.z); o.w = f2bf(f.w);
        *(ushort4*)(d + i) = o;
    }
}

// ---------- GEMM: C[M,N] = A[M,K] @ W[N,K]^T + bias ----------
// 128x128 tile, 4 waves 64x64, BK=32, global_load_lds width-16 staging (m97-style).
// Unpadded LDS tiles: b128 frag reads sit at the 8-phase bandwidth floor anyway.
__global__ __launch_bounds__(256) void gemm_bt(
        const unsigned short* __restrict__ A, const unsigned short* __restrict__ W,
        const float* __restrict__ bias, float* __restrict__ outF,
        unsigned short* __restrict__ outB, int M, int N, int K) {
    __shared__ __align__(16) unsigned short As[128][32];
    __shared__ __align__(16) unsigned short Ws[128][32];
    const int m0 = blockIdx.y * 128, n0 = blockIdx.x * 128;
    const int tid = threadIdx.x, lane = tid & 63, w = tid >> 6;
    const int quad = lane >> 4, lc = lane & 15;
    const int wr = (w >> 1) * 64, wc = (w & 1) * 64;
    const int sr = lane >> 2, sc = (lane & 3) * 8;   // staging row-within-chunk / col (elems)

    f32x4 acc[4][4] = {};

    for (int k0 = 0; k0 < K; k0 += 32) {
        __syncthreads();
        // wave w stages rows [w*32, w*32+32) of both tiles: 2 chunks x 16 rows each
        gld_lds16(A + (size_t)(m0 + w * 32 +      sr) * K + k0 + sc, &As[w * 32     ][0]);
        gld_lds16(A + (size_t)(m0 + w * 32 + 16 + sr) * K + k0 + sc, &As[w * 32 + 16][0]);
        gld_lds16(W + (size_t)(n0 + w * 32 +      sr) * K + k0 + sc, &Ws[w * 32     ][0]);
        gld_lds16(W + (size_t)(n0 + w * 32 + 16 + sr) * K + k0 + sc, &Ws[w * 32 + 16][0]);
        __syncthreads();
        bf16x8 af[4], bw[4];
        #pragma unroll
        for (int i = 0; i < 4; ++i) af[i] = *(const bf16x8*)&As[wr + i * 16 + lc][quad * 8];
        #pragma unroll
        for (int j = 0; j < 4; ++j) bw[j] = *(const bf16x8*)&Ws[wc + j * 16 + lc][quad * 8];
        #pragma unroll
        for (int i = 0; i < 4; ++i)
            #pragma unroll
            for (int j = 0; j < 4; ++j)
                acc[i][j] = __builtin_amdgcn_mfma_f32_16x16x32_bf16(af[i], bw[j], acc[i][j], 0, 0, 0);
    }

    #pragma unroll
    for (int j = 0; j < 4; ++j) {
        int col = n0 + wc + j * 16 + lc;
        float bj = bias[col];
        #pragma unroll
        for (int i = 0; i < 4; ++i) {
            int rowb = m0 + wr + i * 16 + quad * 4;
            #pragma unroll
            for (int r = 0; r < 4; ++r) {
                float v = acc[i][j][r] + bj;
                size_t idx = (size_t)(rowb + r) * N + col;
                if (outB) outB[idx] = f2bf(v);
                else      outF[idx] = v;
            }
        }
    }
}

// ---------- flash attention (S^T / O^T formulation) ----------
// Per wave: 16 q rows (q = lc), S^T[k][q] via mfma(Kfrag, Qfrag).
// Softmax over k: 16 in-register values/lane + 2 cross-quad shuffles.
// O^T[d][q] += V^T P^T keeps q=lc so alpha/l apply per-lane with no shuffles.
// Blocks process q-tile pair (p, 31-p): 33 iterations each, perfectly balanced.
__global__ __launch_bounds__(256, 4) void attn_kernel(
        const unsigned short* __restrict__ Q, const unsigned short* __restrict__ K,
        const unsigned short* __restrict__ V, const int* __restrict__ tmask,
        unsigned short* __restrict__ O) {
    const int T = 2048, C = 1024;
    __shared__ __align__(16) unsigned short Kl[64][72];    // [kv][d]
    __shared__ __align__(16) unsigned short VT[64][72];    // [d][kv]
    __shared__ __align__(16) unsigned short Pl[4][16][72]; // per-wave P[q][k]
    __shared__ float maskf[64];

    const int pair = blockIdx.x;          // 0..15
    const int bn = blockIdx.y;            // b*16 + head
    const int b = bn >> 4, h = bn & 15;
    const int tid = threadIdx.x, w = tid >> 6, lane = tid & 63;
    const int quad = lane >> 4, lc = lane & 15;
    const float NEG_INF = -__builtin_inff();

    #pragma unroll 1
    for (int half = 0; half < 2; ++half) {
        const int qt = half ? (31 - pair) : pair;

        size_t qrow = (size_t)(b * T + qt * 64 + w * 16 + lc) * C + h * 64;
        bf16x8 qb0 = *(const bf16x8*)(Q + qrow + quad * 8);
        bf16x8 qb1 = *(const bf16x8*)(Q + qrow + 32 + quad * 8);

        f32x4 oaccT[4] = {};                   // [jd]: d = jd*16+quad*4+r, q = lc
        float m = NEG_INF, l = 0.f;
        const int qg = qt * 64 + w * 16 + lc;

        for (int kt = 0; kt <= qt; ++kt) {
            __syncthreads();
            {   // K tile row-major
                int r = tid >> 2, c16 = (tid & 3) * 16;
                size_t g = (size_t)(b * T + kt * 64 + r) * C + h * 64 + c16;
                *(bf16x8*)&Kl[r][c16]     = *(const bf16x8*)(K + g);
                *(bf16x8*)&Kl[r][c16 + 8] = *(const bf16x8*)(K + g + 8);
            }
            {   // V transposed, packed pair-of-rows writes (b32)
                int r0 = (tid & 31) * 2, c8 = (tid >> 5) * 8;
                size_t g = (size_t)(b * T + kt * 64 + r0) * C + h * 64 + c8;
                bf16x8 v0 = *(const bf16x8*)(V + g);
                bf16x8 v1 = *(const bf16x8*)(V + g + C);
                #pragma unroll
                for (int i = 0; i < 8; ++i) {
                    unsigned pk = (unsigned short)v0[i] | ((unsigned)(unsigned short)v1[i] << 16);
                    *(unsigned*)&VT[c8 + i][r0] = pk;
                }
            }
            if (tid < 64)
                maskf[tid] = tmask[b * T + kt * 64 + tid] ? 0.0f : NEG_INF;
            __syncthreads();

            // S^T = K Q^T : A = K rows, B = Q rows
            f32x4 sacc[4] = {};
            #pragma unroll
            for (int j = 0; j < 4; ++j) {
                bf16x8 ka0 = *(const bf16x8*)&Kl[j * 16 + lc][quad * 8];
                bf16x8 ka1 = *(const bf16x8*)&Kl[j * 16 + lc][32 + quad * 8];
                sacc[j] = __builtin_amdgcn_mfma_f32_16x16x32_bf16(ka0, qb0, sacc[j], 0, 0, 0);
                sacc[j] = __builtin_amdgcn_mfma_f32_16x16x32_bf16(ka1, qb1, sacc[j], 0, 0, 0);
            }

            // scale + causal + token mask; k = kt*64 + j*16 + quad*4 + r, q = qg
            float s[4][4];
            float mx = NEG_INF;
            #pragma unroll
            for (int j = 0; j < 4; ++j) {
                f32x4 mk = *(const f32x4*)&maskf[j * 16 + quad * 4];
                #pragma unroll
                for (int r = 0; r < 4; ++r) {
                    int kg = kt * 64 + j * 16 + quad * 4 + r;
                    float sv = sacc[j][r] * 0.125f + mk[r];
                    if (kg > qg) sv = NEG_INF;
                    s[j][r] = sv;
                    mx = fmaxf(mx, sv);
                }
            }
            mx = fmaxf(mx, __shfl_xor(mx, 16, 64));
            mx = fmaxf(mx, __shfl_xor(mx, 32, 64));
            float mnew = fmaxf(m, mx);
            float alpha = __expf(m - mnew);
            m = mnew;
            float ps = 0.f;
            #pragma unroll
            for (int j = 0; j < 4; ++j)
                #pragma unroll
                for (int r = 0; r < 4; ++r) {
                    float p = __expf(s[j][r] - mnew);
                    s[j][r] = p;
                    ps += p;
                }
            ps += __shfl_xor(ps, 16, 64);
            ps += __shfl_xor(ps, 32, 64);
            l = l * alpha + ps;
            #pragma unroll
            for (int jd = 0; jd < 4; ++jd) oaccT[jd] *= alpha;

            // P[q][k] rows to LDS: 4x ds_write_b64, then B-frags as b128
            #pragma unroll
            for (int j = 0; j < 4; ++j) {
                ushort4 pk;
                pk.x = f2bf(s[j][0]); pk.y = f2bf(s[j][1]);
                pk.z = f2bf(s[j][2]); pk.w = f2bf(s[j][3]);
                *(ushort4*)&Pl[w][lc][j * 16 + quad * 4] = pk;
            }
            bf16x8 pb0 = *(const bf16x8*)&Pl[w][lc][quad * 8];
            bf16x8 pb1 = *(const bf16x8*)&Pl[w][lc][32 + quad * 8];

            // O^T += V^T P^T : A = VT rows, B = P rows
            #pragma unroll
            for (int jd = 0; jd < 4; ++jd) {
                bf16x8 va0 = *(const bf16x8*)&VT[jd * 16 + lc][quad * 8];
                bf16x8 va1 = *(const bf16x8*)&VT[jd * 16 + lc][32 + quad * 8];
                oaccT[jd] = __builtin_amdgcn_mfma_f32_16x16x32_bf16(va0, pb0, oaccT[jd], 0, 0, 0);
                oaccT[jd] = __builtin_amdgcn_mfma_f32_16x16x32_bf16(va1, pb1, oaccT[jd], 0, 0, 0);
            }
        }

        // epilogue: q = lc per lane; pack 4 consecutive d as 8B store
        float inv = 1.0f / l;
        size_t orow = (size_t)(b * T + qt * 64 + w * 16 + lc) * C + h * 64;
        #pragma unroll
        for (int jd = 0; jd < 4; ++jd) {
            ushort4 o4;
            o4.x = f2bf(oaccT[jd][0] * inv);
            o4.y = f2bf(oaccT[jd][1] * inv);
            o4.z = f2bf(oaccT[jd][2] * inv);
            o4.w = f2bf(oaccT[jd][3] * inv);
            *(ushort4*)(O + orow + jd * 16 + quad * 4) = o4;
        }
    }
}

extern "C" void kernel_launch(void* const* d_in, const int* in_sizes, int n_in,
                              void* d_out, int out_size, void* d_ws, size_t ws_size,
                              hipStream_t stream) {
    const float* x  = (const float*)d_in[0];
    const int* tm   = (const int*)d_in[1];
    const float* wq = (const float*)d_in[2]; const float* bq = (const float*)d_in[3];
    const float* wk = (const float*)d_in[4]; const float* bk = (const float*)d_in[5];
    const float* wv = (const float*)d_in[6]; const float* bv = (const float*)d_in[7];
    const float* wp = (const float*)d_in[8]; const float* bp = (const float*)d_in[9];
    float* out = (float*)d_out;

    const int Bv = 4, Tv = 2048, Cv = 1024;
    const size_t MT = (size_t)Bv * Tv;           // 8192 rows
    const size_t XN = MT * Cv;
    const size_t WN = (size_t)Cv * Cv;

    unsigned short* xb  = (unsigned short*)d_ws;
    unsigned short* wqb = xb  + XN;
    unsigned short* wkb = wqb + WN;
    unsigned short* wvb = wkb + WN;
    unsigned short* wpb = wvb + WN;
    unsigned short* Qb  = wpb + WN;
    unsigned short* Kb  = Qb + XN;
    unsigned short* Vb  = Kb + XN;
    unsigned short* Ab  = xb;                    // attn output reuses xb

    cvt_f32_bf16<<<XN / 1024, 256, 0, stream>>>(x, xb, (int)XN);
    cvt4_f32_bf16<<<dim3(WN / 1024, 4), 256, 0, stream>>>(wq, wk, wv, wp, wqb, wkb, wvb, wpb, (int)WN);

    dim3 gg(Cv / 128, MT / 128);                 // (8, 64)
    gemm_bt<<<gg, 256, 0, stream>>>(xb, wqb, bq, nullptr, Qb, (int)MT, Cv, Cv);
    gemm_bt<<<gg, 256, 0, stream>>>(xb, wkb, bk, nullptr, Kb, (int)MT, Cv, Cv);
    gemm_bt<<<gg, 256, 0, stream>>>(xb, wvb, bv, nullptr, Vb, (int)MT, Cv, Cv);

    attn_kernel<<<dim3(16, Bv * 16), 256, 0, stream>>>(Qb, Kb, Vb, tm, Ab);

    gemm_bt<<<gg, 256, 0, stream>>>(Ab, wpb, bp, out, nullptr, (int)MT, Cv, Cv);
}